// Round 1
// baseline (271.453 us; speedup 1.0000x reference)
//
#include <hip/hip_runtime.h>

// QuantizedSpectralConv on MI355X.
// Shapes: x [8,32,256,256] f32; W Tucker: core[16,16,16,9] F0[32,16] F1[32,16]
// F2[32,16] F3[17,9] (complex, quantized int in [0,254], deq = q*scale+min).
// Active spectral window: kx in [112,144), ky in [56,73) of the (256,129) rfft2.
// out = irfft2(sparse mixed spectrum) + bias, norm="forward".

__device__ __forceinline__ float2 cfma(float2 a, float2 b, float2 c) {
    c.x = fmaf(a.x, b.x, fmaf(-a.y, b.y, c.x));
    c.y = fmaf(a.x, b.y, fmaf(a.y, b.x, c.y));
    return c;
}

// ---------------- dequantize core + factors ----------------
__global__ __launch_bounds__(256) void dequant_kernel(
    const int* __restrict__ q_core, const int* __restrict__ q_f0,
    const int* __restrict__ q_f1, const int* __restrict__ q_f2,
    const int* __restrict__ q_f3,
    const float* __restrict__ core_scale, const float* __restrict__ core_min,
    const float* __restrict__ f_scales, const float* __restrict__ f_mins,
    float2* __restrict__ core, float2* __restrict__ F0, float2* __restrict__ F1,
    float2* __restrict__ F2, float2* __restrict__ F3)
{
    int tid = blockIdx.x * 256 + threadIdx.x;
    if (tid < 36864) {  // core 16*16*16*9
        float s = *core_scale, m = *core_min;
        core[tid] = make_float2(q_core[2*tid] * s + m, q_core[2*tid+1] * s + m);
    } else if (tid < 37376) {  // F0 32*16
        int e = tid - 36864; float s = f_scales[0], m = f_mins[0];
        F0[e] = make_float2(q_f0[2*e] * s + m, q_f0[2*e+1] * s + m);
    } else if (tid < 37888) {  // F1 32*16
        int e = tid - 37376; float s = f_scales[1], m = f_mins[1];
        F1[e] = make_float2(q_f1[2*e] * s + m, q_f1[2*e+1] * s + m);
    } else if (tid < 38400) {  // F2 32*16
        int e = tid - 37888; float s = f_scales[2], m = f_mins[2];
        F2[e] = make_float2(q_f2[2*e] * s + m, q_f2[2*e+1] * s + m);
    } else if (tid < 38553) {  // F3 17*9
        int e = tid - 38400; float s = f_scales[3], m = f_mins[3];
        F3[e] = make_float2(q_f3[2*e] * s + m, q_f3[2*e+1] * s + m);
    }
}

// ---------------- Tucker contractions ----------------
// T1[a,j,k,l] = sum_i F0[a,i] * core[i,j,k,l]      (32,16,16,9)
__global__ __launch_bounds__(256) void t1_kernel(const float2* __restrict__ F0,
                                                 const float2* __restrict__ core,
                                                 float2* __restrict__ T1)
{
    int tid = blockIdx.x * 256 + threadIdx.x;
    if (tid >= 73728) return;
    int l = tid % 9, k = (tid / 9) % 16, j = (tid / 144) % 16, a = tid / 2304;
    float2 acc = make_float2(0.f, 0.f);
    for (int i = 0; i < 16; ++i)
        acc = cfma(F0[a*16 + i], core[((i*16 + j)*16 + k)*9 + l], acc);
    T1[tid] = acc;
}

// T2[a,b,k,l] = sum_j F1[b,j] * T1[a,j,k,l]        (32,32,16,9)
__global__ __launch_bounds__(256) void t2_kernel(const float2* __restrict__ F1,
                                                 const float2* __restrict__ T1,
                                                 float2* __restrict__ T2)
{
    int tid = blockIdx.x * 256 + threadIdx.x;
    if (tid >= 147456) return;
    int l = tid % 9, k = (tid / 9) % 16, b = (tid / 144) % 32, a = tid / 4608;
    float2 acc = make_float2(0.f, 0.f);
    for (int j = 0; j < 16; ++j)
        acc = cfma(F1[b*16 + j], T1[((a*16 + j)*16 + k)*9 + l], acc);
    T2[tid] = acc;
}

// T3[a,b,c,l] = sum_k F2[c,k] * T2[a,b,k,l]        (32,32,32,9)
__global__ __launch_bounds__(256) void t3_kernel(const float2* __restrict__ F2,
                                                 const float2* __restrict__ T2,
                                                 float2* __restrict__ T3)
{
    int tid = blockIdx.x * 256 + threadIdx.x;
    if (tid >= 294912) return;
    int l = tid % 9, c = (tid / 9) % 32, b = (tid / 288) % 32, a = tid / 9216;
    float2 acc = make_float2(0.f, 0.f);
    for (int k = 0; k < 16; ++k)
        acc = cfma(F2[c*16 + k], T2[((a*32 + b)*16 + k)*9 + l], acc);
    T3[tid] = acc;
}

// W4[(c*17+d)*1024 + a*32 + b] = sum_l F3[d,l] * T3[a,b,c,l]   mode-major
__global__ __launch_bounds__(256) void w4_kernel(const float2* __restrict__ F3,
                                                 const float2* __restrict__ T3,
                                                 float2* __restrict__ W4)
{
    int tid = blockIdx.x * 256 + threadIdx.x;
    if (tid >= 557056) return;
    int b = tid % 32, a = (tid / 32) % 32, d = (tid / 1024) % 17, c = tid / 17408;
    float2 acc = make_float2(0.f, 0.f);
    for (int l = 0; l < 9; ++l)
        acc = cfma(F3[d*9 + l], T3[((a*32 + b)*32 + c)*9 + l], acc);
    W4[tid] = acc;
}

// ---------------- forward partial DFT along w ----------------
// A1[row, ky] = sum_w x[row, w] * exp(-2pi i (ky+56) w / 256), row = b*Cin*H flat
#define ROWS_A 15
__global__ __launch_bounds__(256) void fwd_w_kernel(const float* __restrict__ x,
                                                    float2* __restrict__ A1,
                                                    int nrows)
{
    __shared__ float2 tbl[256];
    __shared__ float xs[ROWS_A * 256];
    int tid = threadIdx.x;
    tbl[tid] = make_float2(cospif(tid / 128.f), -sinpif(tid / 128.f));
    int row0 = blockIdx.x * ROWS_A;
    for (int idx = tid; idx < ROWS_A * 256; idx += 256) {
        int r = idx >> 8, w = idx & 255;
        int row = row0 + r;
        xs[idx] = (row < nrows) ? x[row * 256 + w] : 0.f;
    }
    __syncthreads();
    if (tid < ROWS_A * 17) {
        int r = tid / 17, ky = tid % 17;
        int row = row0 + r;
        if (row < nrows) {
            int kk = ky + 56;
            float ar = 0.f, ai = 0.f;
            const float* xr = &xs[r * 256];
            for (int w = 0; w < 256; ++w) {
                float2 t = tbl[(kk * w) & 255];
                float xv = xr[w];
                ar = fmaf(xv, t.x, ar);
                ai = fmaf(xv, t.y, ai);
            }
            A1[row * 17 + ky] = make_float2(ar, ai);
        }
    }
}

// ---------------- forward partial DFT along h ----------------
// X[(kx*17+ky)*256 + bi] = (1/65536) * sum_h A1[bi,h,ky] * exp(-2pi i (kx+112) h/256)
__global__ __launch_bounds__(256) void fwd_h_kernel(const float2* __restrict__ A1,
                                                    float2* __restrict__ X)
{
    __shared__ float2 tbl[256];
    __shared__ float2 As[256 * 17];
    int tid = threadIdx.x, bi = blockIdx.x;
    tbl[tid] = make_float2(cospif(tid / 128.f), -sinpif(tid / 128.f));
    for (int idx = tid; idx < 4352; idx += 256) As[idx] = A1[bi * 4352 + idx];
    __syncthreads();
    const float inv = 1.0f / 65536.0f;
    for (int out = tid; out < 544; out += 256) {
        int kx = out / 17, ky = out % 17;
        int kk = kx + 112;
        float2 acc = make_float2(0.f, 0.f);
        for (int h = 0; h < 256; ++h)
            acc = cfma(As[h * 17 + ky], tbl[(kk * h) & 255], acc);
        X[out * 256 + bi] = make_float2(acc.x * inv, acc.y * inv);
    }
}

// ---------------- per-mode channel mixing ----------------
// Mx[mode*256 + b*32+o] = sum_i X[mode*256 + b*32+i] * W4[mode*1024 + i*32+o]
__global__ __launch_bounds__(256) void mix_kernel(const float2* __restrict__ X,
                                                  const float2* __restrict__ W4,
                                                  float2* __restrict__ Mx)
{
    __shared__ float2 Xs[256];
    __shared__ float2 Ws[1024];
    int tid = threadIdx.x, mode = blockIdx.x;
    Xs[tid] = X[mode * 256 + tid];
    for (int idx = tid; idx < 1024; idx += 256) Ws[idx] = W4[mode * 1024 + idx];
    __syncthreads();
    int b = tid >> 5, o = tid & 31;
    float2 acc = make_float2(0.f, 0.f);
    for (int i = 0; i < 32; ++i)
        acc = cfma(Xs[b * 32 + i], Ws[i * 32 + o], acc);
    Mx[mode * 256 + tid] = acc;
}

// ---------------- inverse DFT along h ----------------
// T[(bo*256+h)*17 + ky] = sum_kx Mx[(kx*17+ky)*256 + bo] * exp(+2pi i (kx+112) h/256)
__global__ __launch_bounds__(256) void inv_h_kernel(const float2* __restrict__ Mx,
                                                    float2* __restrict__ T)
{
    __shared__ float2 tbl[256];
    __shared__ float2 ms[544];
    int tid = threadIdx.x, bo = blockIdx.x;
    tbl[tid] = make_float2(cospif(tid / 128.f), -sinpif(tid / 128.f));
    for (int idx = tid; idx < 544; idx += 256) ms[idx] = Mx[idx * 256 + bo];
    __syncthreads();
    int h = tid;
    float accr[17], acci[17];
#pragma unroll
    for (int ky = 0; ky < 17; ++ky) { accr[ky] = 0.f; acci[ky] = 0.f; }
    for (int kx = 0; kx < 32; ++kx) {
        float2 t = tbl[((kx + 112) * h) & 255];
        float tr = t.x, ti = -t.y;  // e^{+i...} = conj(table)
#pragma unroll
        for (int ky = 0; ky < 17; ++ky) {
            float2 m = ms[kx * 17 + ky];
            accr[ky] = fmaf(m.x, tr, fmaf(-m.y, ti, accr[ky]));
            acci[ky] = fmaf(m.x, ti, fmaf(m.y, tr, acci[ky]));
        }
    }
    float2* Trow = &T[(bo * 256 + h) * 17];
#pragma unroll
    for (int ky = 0; ky < 17; ++ky) Trow[ky] = make_float2(accr[ky], acci[ky]);
}

// ---------------- inverse DFT along w (real output) + bias ----------------
// out[row, w] = 2 * Re( sum_ky T[row,ky] * exp(+2pi i (ky+56) w/256) ) + bias[o]
#define ROWS_E 8
__global__ __launch_bounds__(256) void inv_w_kernel(const float2* __restrict__ T,
                                                    const int* __restrict__ q_bias,
                                                    const float* __restrict__ b_scale,
                                                    const float* __restrict__ b_min,
                                                    float* __restrict__ out)
{
    __shared__ float2 tbl[256];
    __shared__ float2 Ts[ROWS_E * 17];
    int tid = threadIdx.x;
    int row0 = blockIdx.x * ROWS_E;           // global row = (b*32+o)*256 + h
    int o = (row0 >> 8) & 31;
    tbl[tid] = make_float2(cospif(tid / 128.f), -sinpif(tid / 128.f));
    if (tid < ROWS_E * 17) Ts[tid] = T[row0 * 17 + tid];
    __syncthreads();
    float bias = q_bias[o] * (*b_scale) + (*b_min);
    int w = tid;
    for (int r = 0; r < ROWS_E; ++r) {
        float acc = 0.f;
#pragma unroll
        for (int ky = 0; ky < 17; ++ky) {
            float2 t = tbl[((ky + 56) * w) & 255];
            float2 v = Ts[r * 17 + ky];
            // Re(v * e^{+i}) with table = e^{-i}: v.x*t.x + v.y*t.y
            acc = fmaf(v.x, t.x, fmaf(v.y, t.y, acc));
        }
        out[(row0 + r) * 256 + w] = 2.f * acc + bias;
    }
}

extern "C" void kernel_launch(void* const* d_in, const int* in_sizes, int n_in,
                              void* d_out, int out_size, void* d_ws, size_t ws_size,
                              hipStream_t stream) {
    const float* x          = (const float*)d_in[0];
    const float* core_scale = (const float*)d_in[1];
    const float* core_min   = (const float*)d_in[2];
    const float* f_scales   = (const float*)d_in[3];
    const float* f_mins     = (const float*)d_in[4];
    const float* b_scale    = (const float*)d_in[5];
    const float* b_min      = (const float*)d_in[6];
    const int* q_core = (const int*)d_in[7];
    const int* q_f0   = (const int*)d_in[8];
    const int* q_f1   = (const int*)d_in[9];
    const int* q_f2   = (const int*)d_in[10];
    const int* q_f3   = (const int*)d_in[11];
    const int* q_bias = (const int*)d_in[12];
    float* out = (float*)d_out;

    // workspace layout (float2 units)
    float2* ws = (float2*)d_ws;
    float2* A1   = ws;                 // 1,114,112   [65536 rows][17]  (aliased by T)
    float2* T    = ws;                 // alias: A1 dead after fwd_h
    float2* W4   = ws + 1114112;       //   557,056   [544 modes][32 i][32 o]
    float2* X    = W4 + 557056;        //   139,264   [544 modes][256 bi]
    float2* Mx   = X + 139264;         //   139,264   [544 modes][256 bo]
    float2* core = Mx + 139264;        //    36,864
    float2* T1   = core + 36864;       //    73,728
    float2* T2   = T1 + 73728;         //   147,456
    float2* T3   = T2 + 147456;        //   294,912
    float2* F0   = T3 + 294912;        //       512
    float2* F1   = F0 + 512;           //       512
    float2* F2   = F1 + 512;           //       512
    float2* F3   = F2 + 512;           //       153
    (void)ws_size; (void)n_in; (void)in_sizes; (void)out_size;

    const int nrows = 8 * 32 * 256;    // 65536

    // weight pipeline
    dequant_kernel<<<151, 256, 0, stream>>>(q_core, q_f0, q_f1, q_f2, q_f3,
                                            core_scale, core_min, f_scales, f_mins,
                                            core, F0, F1, F2, F3);
    t1_kernel<<<288, 256, 0, stream>>>(F0, core, T1);
    t2_kernel<<<576, 256, 0, stream>>>(F1, T1, T2);
    t3_kernel<<<1152, 256, 0, stream>>>(F2, T2, T3);
    w4_kernel<<<2176, 256, 0, stream>>>(F3, T3, W4);

    // data pipeline
    fwd_w_kernel<<<(nrows + ROWS_A - 1) / ROWS_A, 256, 0, stream>>>(x, A1, nrows);
    fwd_h_kernel<<<256, 256, 0, stream>>>(A1, X);
    mix_kernel<<<544, 256, 0, stream>>>(X, W4, Mx);
    inv_h_kernel<<<256, 256, 0, stream>>>(Mx, T);
    inv_w_kernel<<<nrows / ROWS_E, 256, 0, stream>>>(T, q_bias, b_scale, b_min, out);
}

// Round 2
// 248.600 us; speedup vs baseline: 1.0919x; 1.0919x over previous
//
#include <hip/hip_runtime.h>

// QuantizedSpectralConv on MI355X (gfx950).
// x [8,32,256,256] f32; Tucker: core[16,16,16,9] F0[32,16] F1[32,16] F2[32,16]
// F3[17,9] complex, deq = q*scale+min. Active window: kx in [112,144),
// ky in [56,73) of the (256,129) rfft2. norm="forward" (1/65536 on fwd).
//
// Layouts (float2 workspace):
//   A1 [17 ky][256 bi][256 h]   partial DFT along w
//   X  [544 mode][256 bi]       mode = kx*17+ky, scaled 1/65536
//   W4 [544 mode][32 i][32 o]
//   Mx [544 mode][256 bo]
// LDS rule: addresses wave-uniform (broadcast) or lane-consecutive only.

__device__ __forceinline__ float2 cfma(float2 a, float2 b, float2 c) {
    c.x = fmaf(a.x, b.x, fmaf(-a.y, b.y, c.x));
    c.y = fmaf(a.x, b.y, fmaf(a.y, b.x, c.y));
    return c;
}
__device__ __forceinline__ float2 cmul(float2 a, float2 b) {
    return make_float2(a.x*b.x - a.y*b.y, a.x*b.y + a.y*b.x);
}

// ================= weights: dequant + full Tucker per mode =================
// Per block (mode m = c*17+d): C2[i,j] = sum_{k,l} core[i,j,k,l]*F2[c,k]*F3[d,l]
// A2[i,b] = sum_j C2[i,j]*F1[b,j];  W4[m,a,b] = sum_i F0[a,i]*A2[i,b]
__global__ __launch_bounds__(256) void weights_kernel(
    const int* __restrict__ q_core, const int* __restrict__ q_f0,
    const int* __restrict__ q_f1, const int* __restrict__ q_f2,
    const int* __restrict__ q_f3,
    const float* __restrict__ core_scale, const float* __restrict__ core_min,
    const float* __restrict__ f_scales, const float* __restrict__ f_mins,
    float2* __restrict__ W4)
{
    __shared__ float2 F0s[512], F1s[512], skl[144];
    __shared__ float2 C2p[16*17];   // pad 17: conflict-free i-strided reads
    __shared__ float2 A2p[16*33];   // pad 33
    int t = threadIdx.x, m = blockIdx.x;
    int c = m / 17, d = m % 17;
    float cs = *core_scale, cm = *core_min;
    float s0 = f_scales[0], m0 = f_mins[0];
    float s1 = f_scales[1], m1 = f_mins[1];

    for (int e = t; e < 512; e += 256) {
        F0s[e] = make_float2(q_f0[2*e]*s0 + m0, q_f0[2*e+1]*s0 + m0);
        F1s[e] = make_float2(q_f1[2*e]*s1 + m1, q_f1[2*e+1]*s1 + m1);
    }
    if (t < 144) {
        int k = t / 9, l = t % 9;
        float s2 = f_scales[2], m2 = f_mins[2];
        float s3 = f_scales[3], m3 = f_mins[3];
        float2 f2 = make_float2(q_f2[2*(c*16+k)]*s2 + m2, q_f2[2*(c*16+k)+1]*s2 + m2);
        float2 f3 = make_float2(q_f3[2*(d*9+l)]*s3 + m3, q_f3[2*(d*9+l)+1]*s3 + m3);
        skl[t] = cmul(f2, f3);
    }
    __syncthreads();
    {   // phase 1: thread t = (i,j)
        int i = t >> 4, j = t & 15;
        const int4* qc = (const int4*)(q_core + t * 288);  // t == i*16+j
        float2 acc = make_float2(0.f, 0.f);
#pragma unroll 8
        for (int u = 0; u < 72; ++u) {
            int4 q = qc[u];
            float2 e0 = make_float2(q.x*cs + cm, q.y*cs + cm);
            float2 e1 = make_float2(q.z*cs + cm, q.w*cs + cm);
            acc = cfma(e0, skl[2*u], acc);
            acc = cfma(e1, skl[2*u+1], acc);
        }
        C2p[i*17 + j] = acc;
    }
    __syncthreads();
#pragma unroll
    for (int r = 0; r < 2; ++r) {   // phase 2: e = (b,i), 512 outputs
        int e = t + r*256; int i = e & 15, b = e >> 4;
        float2 acc = make_float2(0.f, 0.f);
#pragma unroll
        for (int j = 0; j < 16; ++j)
            acc = cfma(C2p[i*17 + j], F1s[b*16 + j], acc);
        A2p[i*33 + b] = acc;
    }
    __syncthreads();
    {   // phase 3: 4 outputs per thread
        int b = t & 31, a0 = t >> 5;
#pragma unroll
        for (int q = 0; q < 4; ++q) {
            int a = a0 + 8*q;
            float2 acc = make_float2(0.f, 0.f);
#pragma unroll
            for (int i = 0; i < 16; ++i)
                acc = cfma(F0s[a*16 + i], A2p[i*33 + b], acc);
            W4[m*1024 + a*32 + b] = acc;
        }
    }
}

// ================= forward partial DFT along w =================
// A1[ky][bi][h] = sum_w x[bi][h][w] * e^{-2pi i (ky+56) w/256}
// lanes = rows (conflict-free stride-65 LDS), ky-group per wave (broadcast tbl),
// w-quadrant symmetry: t(kk,w+64q) = t(kk,w) * (-i)^{(kk&3)*q}  (sign-wired).
template<int P>
__device__ __forceinline__ void quad_acc(float& ar, float& ai, float xv, float tx, float ty) {
    if (P == 0) { ar = fmaf(xv, tx, ar);  ai = fmaf(xv, ty, ai); }
    if (P == 1) { ar = fmaf(xv, ty, ar);  ai = fmaf(-xv, tx, ai); }   // *(-i)
    if (P == 2) { ar = fmaf(-xv, tx, ar); ai = fmaf(-xv, ty, ai); }   // *(-1)
    if (P == 3) { ar = fmaf(-xv, ty, ar); ai = fmaf(xv, tx, ai); }    // *(+i)
}

template<int KY0, int NKY>
__device__ __forceinline__ void fwdw_body(int lane, int row0, const float* xs,
                                          const float2* tbl, float2* __restrict__ A1)
{
    float ar[NKY], ai[NKY];
#pragma unroll
    for (int j = 0; j < NKY; ++j) { ar[j] = 0.f; ai[j] = 0.f; }
    int idx[NKY];
#pragma unroll
    for (int j = 0; j < NKY; ++j) idx[j] = 0;
    for (int w = 0; w < 64; ++w) {
        float xv0 = xs[w*65 + lane];
        float xv1 = xs[(w+64)*65 + lane];
        float xv2 = xs[(w+128)*65 + lane];
        float xv3 = xs[(w+192)*65 + lane];
#pragma unroll
        for (int j = 0; j < NKY; ++j) {
            constexpr int KK = 0;  (void)KK;
            const int kk = KY0 + j + 56;
            float2 t = tbl[idx[j]];
            idx[j] = (idx[j] + kk) & 255;
            constexpr int p = (KY0 + 56) % 4;     // adjusted below per j
            const int pj = (p + j) & 3;
            // pj is compile-time because j is an unrolled constant:
            switch (pj) {
                case 0:
                    quad_acc<0>(ar[j], ai[j], xv0, t.x, t.y);
                    quad_acc<0>(ar[j], ai[j], xv1, t.x, t.y);
                    quad_acc<0>(ar[j], ai[j], xv2, t.x, t.y);
                    quad_acc<0>(ar[j], ai[j], xv3, t.x, t.y);
                    break;
                case 1:
                    quad_acc<0>(ar[j], ai[j], xv0, t.x, t.y);
                    quad_acc<1>(ar[j], ai[j], xv1, t.x, t.y);
                    quad_acc<2>(ar[j], ai[j], xv2, t.x, t.y);
                    quad_acc<3>(ar[j], ai[j], xv3, t.x, t.y);
                    break;
                case 2:
                    quad_acc<0>(ar[j], ai[j], xv0, t.x, t.y);
                    quad_acc<2>(ar[j], ai[j], xv1, t.x, t.y);
                    quad_acc<0>(ar[j], ai[j], xv2, t.x, t.y);
                    quad_acc<2>(ar[j], ai[j], xv3, t.x, t.y);
                    break;
                default:
                    quad_acc<0>(ar[j], ai[j], xv0, t.x, t.y);
                    quad_acc<3>(ar[j], ai[j], xv1, t.x, t.y);
                    quad_acc<2>(ar[j], ai[j], xv2, t.x, t.y);
                    quad_acc<1>(ar[j], ai[j], xv3, t.x, t.y);
                    break;
            }
        }
    }
    int row = row0 + lane;
#pragma unroll
    for (int j = 0; j < NKY; ++j)
        A1[(KY0 + j)*65536 + row] = make_float2(ar[j], ai[j]);
}

__global__ __launch_bounds__(256) void fwd_w_kernel(const float* __restrict__ x,
                                                    float2* __restrict__ A1)
{
    __shared__ float2 tbl[256];
    __shared__ float xs[256*65];        // [w][row] padded
    int tid = threadIdx.x;
    tbl[tid] = make_float2(cospif(tid * (1.f/128.f)), -sinpif(tid * (1.f/128.f)));
    int row0 = blockIdx.x * 64;
    const float2* xf2 = (const float2*)x;
    for (int i2 = tid; i2 < 8192; i2 += 256) {
        int r = i2 >> 7, w2 = i2 & 127;
        float2 v = xf2[(size_t)(row0 + r)*128 + w2];
        xs[(2*w2)*65 + r]   = v.x;
        xs[(2*w2+1)*65 + r] = v.y;
    }
    __syncthreads();
    int lane = tid & 63, g = tid >> 6;
    if      (g == 0) fwdw_body<0, 5>(lane, row0, xs, tbl, A1);
    else if (g == 1) fwdw_body<5, 4>(lane, row0, xs, tbl, A1);
    else if (g == 2) fwdw_body<9, 4>(lane, row0, xs, tbl, A1);
    else             fwdw_body<13,4>(lane, row0, xs, tbl, A1);
}

// ================= forward partial DFT along h =================
// X[(kx*17+ky)*256+bi] = (1/65536) sum_h A1[ky][bi][h] e^{-2pi i (kx+112)h/256}
// Block = (ky, 16-bi group). lanes = (bi, h-quadrant); partial sums combined by
// shfl_xor; per-lane factor (-i)^{p*q} applied once after the loop.
__global__ __launch_bounds__(256) void fwd_h_kernel(const float2* __restrict__ A1,
                                                    float2* __restrict__ X)
{
    __shared__ float2 tbl[256];
    __shared__ float as_re[4*1104];     // [q][hh*17 + bl], skew 16 floats per q
    __shared__ float as_im[4*1104];
    int tid = threadIdx.x;
    int ky = blockIdx.x >> 4, bi0 = (blockIdx.x & 15) * 16;
    tbl[tid] = make_float2(cospif(tid * (1.f/128.f)), -sinpif(tid * (1.f/128.f)));
    for (int idx = tid; idx < 4096; idx += 256) {
        int b = idx >> 8, h = idx & 255;
        float2 v = A1[ky*65536 + (bi0 + b)*256 + h];
        int ad = (h >> 6)*1104 + (h & 63)*17 + b;
        as_re[ad] = v.x; as_im[ad] = v.y;
    }
    __syncthreads();
    int lane = tid & 63, g = tid >> 6;
    int bl = lane & 15, q = lane >> 4;
    int kx0 = g * 8;
    float2 acc[8];
#pragma unroll
    for (int j = 0; j < 8; ++j) acc[j] = make_float2(0.f, 0.f);
    int base = q*1104 + bl;
    for (int hh = 0; hh < 64; ++hh) {
        float ar = as_re[base + hh*17];
        float ai = as_im[base + hh*17];
#pragma unroll
        for (int j = 0; j < 8; ++j) {
            int kk = kx0 + j + 112;
            float2 t = tbl[(kk * hh) & 255];      // wave-uniform -> broadcast
            acc[j].x = fmaf(ar, t.x, fmaf(-ai, t.y, acc[j].x));
            acc[j].y = fmaf(ar, t.y, fmaf( ai, t.x, acc[j].y));
        }
    }
    // per-lane factor (-i)^{p*q}, p = (kk mod 4) = (j mod 4) since kx0+112 = 0 mod 4
    float2 f1 = make_float2((q == 0) ? 1.f : (q == 2) ? -1.f : 0.f,
                            (q == 1) ? -1.f : (q == 3) ? 1.f : 0.f);
    float2 f2 = cmul(f1, f1), f3 = cmul(f2, f1);
    float2 fq[4] = { make_float2(1.f, 0.f), f1, f2, f3 };
#pragma unroll
    for (int j = 0; j < 8; ++j) {
        float2 a = cmul(acc[j], fq[j & 3]);
        a.x += __shfl_xor(a.x, 16); a.y += __shfl_xor(a.y, 16);
        a.x += __shfl_xor(a.x, 32); a.y += __shfl_xor(a.y, 32);
        acc[j] = a;
    }
    if (q == 0) {
        const float inv = 1.f / 65536.f;
#pragma unroll
        for (int j = 0; j < 8; ++j)
            X[((kx0 + j)*17 + ky)*256 + bi0 + bl] =
                make_float2(acc[j].x * inv, acc[j].y * inv);
    }
}

// ================= per-mode channel mixing =================
__global__ __launch_bounds__(256) void mix_kernel(const float2* __restrict__ X,
                                                  const float2* __restrict__ W4,
                                                  float2* __restrict__ Mx)
{
    __shared__ float2 Xs[256];
    __shared__ float2 Ws[1024];
    int tid = threadIdx.x, mode = blockIdx.x;
    Xs[tid] = X[mode*256 + tid];
    for (int idx = tid; idx < 1024; idx += 256) Ws[idx] = W4[mode*1024 + idx];
    __syncthreads();
    int b = tid >> 5, o = tid & 31;
    float2 acc = make_float2(0.f, 0.f);
#pragma unroll
    for (int i = 0; i < 32; ++i)
        acc = cfma(Xs[b*32 + i], Ws[i*32 + o], acc);
    Mx[mode*256 + tid] = acc;
}

// ================= fused inverse (kx-DFT then w-DFT + bias) =================
template<int KY0, int N>
__device__ __forceinline__ void invh_body(int h, const float2* ms, float2* Ts)
{
    float2 acc[N];
#pragma unroll
    for (int j = 0; j < N; ++j) acc[j] = make_float2(0.f, 0.f);
    for (int kx = 0; kx < 32; ++kx) {
        int n = ((kx + 112) * h) & 255;
        float a = n * (1.f/128.f);
        float cc = cospif(a), ss = sinpif(a);      // e^{+i theta}
#pragma unroll
        for (int j = 0; j < N; ++j) {
            float2 mv = ms[kx*17 + KY0 + j];       // wave-uniform broadcast
            acc[j].x = fmaf(mv.x, cc, fmaf(-mv.y, ss, acc[j].x));
            acc[j].y = fmaf(mv.x, ss, fmaf( mv.y, cc, acc[j].y));
        }
    }
#pragma unroll
    for (int j = 0; j < N; ++j) Ts[h*17 + KY0 + j] = acc[j];
}

__global__ __launch_bounds__(512) void inv_kernel(const float2* __restrict__ Mx,
                                                  const int* __restrict__ q_bias,
                                                  const float* __restrict__ b_scale,
                                                  const float* __restrict__ b_min,
                                                  float* __restrict__ out)
{
    __shared__ float2 ms[544];
    __shared__ float2 Ts[256*17];
    int tid = threadIdx.x, bo = blockIdx.x;
    for (int idx = tid; idx < 544; idx += 512) ms[idx] = Mx[idx*256 + bo];
    __syncthreads();
    {   // phase 1: T[h][ky] = sum_kx Mx[kx][ky] e^{+2pi i (kx+112)h/256}
        int h = tid & 255;
        if (tid < 256) invh_body<0, 9>(h, ms, Ts);
        else           invh_body<9, 8>(h, ms, Ts);
    }
    __syncthreads();
    {   // phase 2: out[row][w] = 2*Re(sum_ky T[h][ky] e^{+2pi i (ky+56)w/256}) + bias
        int w = tid & 255, team = tid >> 8;
        float Ec[17], Es[17];
#pragma unroll
        for (int ky = 0; ky < 17; ++ky) {
            int n = ((ky + 56) * w) & 255;
            float a = n * (1.f/128.f);
            Ec[ky] = cospif(a);
            Es[ky] = -sinpif(a);      // acc += v.x*cos - v.y*sin
        }
        float bias = q_bias[bo & 31] * (*b_scale) + (*b_min);
        float* orow = out + (size_t)bo * 65536;
        for (int rr = 0; rr < 128; ++rr) {
            int h = team*128 + rr;
            float acc = 0.f;
#pragma unroll
            for (int ky = 0; ky < 17; ++ky) {
                float2 v = Ts[h*17 + ky];          // broadcast
                acc = fmaf(v.x, Ec[ky], acc);
                acc = fmaf(v.y, Es[ky], acc);
            }
            orow[h*256 + w] = fmaf(2.f, acc, bias);
        }
    }
}

extern "C" void kernel_launch(void* const* d_in, const int* in_sizes, int n_in,
                              void* d_out, int out_size, void* d_ws, size_t ws_size,
                              hipStream_t stream) {
    const float* x          = (const float*)d_in[0];
    const float* core_scale = (const float*)d_in[1];
    const float* core_min   = (const float*)d_in[2];
    const float* f_scales   = (const float*)d_in[3];
    const float* f_mins     = (const float*)d_in[4];
    const float* b_scale    = (const float*)d_in[5];
    const float* b_min      = (const float*)d_in[6];
    const int* q_core = (const int*)d_in[7];
    const int* q_f0   = (const int*)d_in[8];
    const int* q_f1   = (const int*)d_in[9];
    const int* q_f2   = (const int*)d_in[10];
    const int* q_f3   = (const int*)d_in[11];
    const int* q_bias = (const int*)d_in[12];
    float* out = (float*)d_out;

    float2* ws = (float2*)d_ws;
    float2* A1 = ws;                 // 1,114,112  [17][256 bi][256 h]
    float2* W4 = ws + 1114112;       //   557,056  [544][32][32]
    float2* X  = W4 + 557056;        //   139,264  [544][256]
    float2* Mx = X + 139264;         //   139,264  [544][256]
    (void)ws_size; (void)n_in; (void)in_sizes; (void)out_size;

    weights_kernel<<<544, 256, 0, stream>>>(q_core, q_f0, q_f1, q_f2, q_f3,
                                            core_scale, core_min, f_scales, f_mins, W4);
    fwd_w_kernel<<<1024, 256, 0, stream>>>(x, A1);
    fwd_h_kernel<<<272, 256, 0, stream>>>(A1, X);
    mix_kernel<<<544, 256, 0, stream>>>(X, W4, Mx);
    inv_kernel<<<256, 512, 0, stream>>>(Mx, q_bias, b_scale, b_min, out);
}

// Round 3
// 238.694 us; speedup vs baseline: 1.1372x; 1.0415x over previous
//
#include <hip/hip_runtime.h>

// QuantizedSpectralConv on MI355X (gfx950).
// x [8,32,256,256] f32; Tucker: core[16,16,16,9] F0[32,16] F1[32,16] F2[32,16]
// F3[17,9] complex, deq = q*scale+min. Active window: kx in [112,144),
// ky in [56,73) of the (256,129) rfft2. norm="forward" (1/65536 on fwd).
//
// Layouts (float2 workspace):
//   A1 [17 ky][256 bi][256 h]   partial DFT along w
//   X  [544 mode][256 bi]       mode = kx*17+ky, scaled 1/65536
//   W4 [544 mode][32 i][32 o]
//   Mx [544 mode][256 bo]
// LDS rule: addresses wave-uniform (broadcast) or lane-consecutive only.

__device__ __forceinline__ float2 cfma(float2 a, float2 b, float2 c) {
    c.x = fmaf(a.x, b.x, fmaf(-a.y, b.y, c.x));
    c.y = fmaf(a.x, b.y, fmaf(a.y, b.x, c.y));
    return c;
}
__device__ __forceinline__ float2 cmul(float2 a, float2 b) {
    return make_float2(a.x*b.x - a.y*b.y, a.x*b.y + a.y*b.x);
}

// ================= weights: dequant + full Tucker per mode =================
__global__ __launch_bounds__(256) void weights_kernel(
    const int* __restrict__ q_core, const int* __restrict__ q_f0,
    const int* __restrict__ q_f1, const int* __restrict__ q_f2,
    const int* __restrict__ q_f3,
    const float* __restrict__ core_scale, const float* __restrict__ core_min,
    const float* __restrict__ f_scales, const float* __restrict__ f_mins,
    float2* __restrict__ W4)
{
    __shared__ float2 F0s[512], F1s[512], skl[144];
    __shared__ float2 C2p[16*17];
    __shared__ float2 A2p[16*33];
    int t = threadIdx.x, m = blockIdx.x;
    int c = m / 17, d = m % 17;
    float cs = *core_scale, cm = *core_min;
    float s0 = f_scales[0], m0 = f_mins[0];
    float s1 = f_scales[1], m1 = f_mins[1];

    for (int e = t; e < 512; e += 256) {
        F0s[e] = make_float2(q_f0[2*e]*s0 + m0, q_f0[2*e+1]*s0 + m0);
        F1s[e] = make_float2(q_f1[2*e]*s1 + m1, q_f1[2*e+1]*s1 + m1);
    }
    if (t < 144) {
        int k = t / 9, l = t % 9;
        float s2 = f_scales[2], m2 = f_mins[2];
        float s3 = f_scales[3], m3 = f_mins[3];
        float2 f2 = make_float2(q_f2[2*(c*16+k)]*s2 + m2, q_f2[2*(c*16+k)+1]*s2 + m2);
        float2 f3 = make_float2(q_f3[2*(d*9+l)]*s3 + m3, q_f3[2*(d*9+l)+1]*s3 + m3);
        skl[t] = cmul(f2, f3);
    }
    __syncthreads();
    {   // phase 1: thread t = (i,j): C2[i,j] = sum_{k,l} core*F2[c,k]*F3[d,l]
        int i = t >> 4, j = t & 15;
        const int4* qc = (const int4*)(q_core + t * 288);
        float2 acc = make_float2(0.f, 0.f);
#pragma unroll 8
        for (int u = 0; u < 72; ++u) {
            int4 q = qc[u];
            float2 e0 = make_float2(q.x*cs + cm, q.y*cs + cm);
            float2 e1 = make_float2(q.z*cs + cm, q.w*cs + cm);
            acc = cfma(e0, skl[2*u], acc);
            acc = cfma(e1, skl[2*u+1], acc);
        }
        C2p[i*17 + j] = acc;
    }
    __syncthreads();
#pragma unroll
    for (int r = 0; r < 2; ++r) {   // phase 2: A2[i,b] = sum_j C2[i,j]*F1[b,j]
        int e = t + r*256; int i = e & 15, b = e >> 4;
        float2 acc = make_float2(0.f, 0.f);
#pragma unroll
        for (int j = 0; j < 16; ++j)
            acc = cfma(C2p[i*17 + j], F1s[b*16 + j], acc);
        A2p[i*33 + b] = acc;
    }
    __syncthreads();
    {   // phase 3: W4[m,a,b] = sum_i F0[a,i]*A2[i,b]
        int b = t & 31, a0 = t >> 5;
#pragma unroll
        for (int q = 0; q < 4; ++q) {
            int a = a0 + 8*q;
            float2 acc = make_float2(0.f, 0.f);
#pragma unroll
            for (int i = 0; i < 16; ++i)
                acc = cfma(F0s[a*16 + i], A2p[i*33 + b], acc);
            W4[m*1024 + a*32 + b] = acc;
        }
    }
}

// ================= forward partial DFT along w =================
template<int P>
__device__ __forceinline__ void quad_acc(float& ar, float& ai, float xv, float tx, float ty) {
    if (P == 0) { ar = fmaf(xv, tx, ar);  ai = fmaf(xv, ty, ai); }
    if (P == 1) { ar = fmaf(xv, ty, ar);  ai = fmaf(-xv, tx, ai); }   // *(-i)
    if (P == 2) { ar = fmaf(-xv, tx, ar); ai = fmaf(-xv, ty, ai); }   // *(-1)
    if (P == 3) { ar = fmaf(-xv, ty, ar); ai = fmaf(xv, tx, ai); }    // *(+i)
}

template<int KY0, int NKY>
__device__ __forceinline__ void fwdw_body(int lane, int row0, const float* xs,
                                          const float2* tbl, float2* __restrict__ A1)
{
    float ar[NKY], ai[NKY];
#pragma unroll
    for (int j = 0; j < NKY; ++j) { ar[j] = 0.f; ai[j] = 0.f; }
    int idx[NKY];
#pragma unroll
    for (int j = 0; j < NKY; ++j) idx[j] = 0;
    for (int w = 0; w < 64; ++w) {
        float xv0 = xs[w*65 + lane];
        float xv1 = xs[(w+64)*65 + lane];
        float xv2 = xs[(w+128)*65 + lane];
        float xv3 = xs[(w+192)*65 + lane];
#pragma unroll
        for (int j = 0; j < NKY; ++j) {
            const int kk = KY0 + j + 56;
            float2 t = tbl[idx[j]];
            idx[j] = (idx[j] + kk) & 255;
            const int pj = (KY0 + 56 + j) & 3;
            switch (pj) {
                case 0:
                    quad_acc<0>(ar[j], ai[j], xv0, t.x, t.y);
                    quad_acc<0>(ar[j], ai[j], xv1, t.x, t.y);
                    quad_acc<0>(ar[j], ai[j], xv2, t.x, t.y);
                    quad_acc<0>(ar[j], ai[j], xv3, t.x, t.y);
                    break;
                case 1:
                    quad_acc<0>(ar[j], ai[j], xv0, t.x, t.y);
                    quad_acc<1>(ar[j], ai[j], xv1, t.x, t.y);
                    quad_acc<2>(ar[j], ai[j], xv2, t.x, t.y);
                    quad_acc<3>(ar[j], ai[j], xv3, t.x, t.y);
                    break;
                case 2:
                    quad_acc<0>(ar[j], ai[j], xv0, t.x, t.y);
                    quad_acc<2>(ar[j], ai[j], xv1, t.x, t.y);
                    quad_acc<0>(ar[j], ai[j], xv2, t.x, t.y);
                    quad_acc<2>(ar[j], ai[j], xv3, t.x, t.y);
                    break;
                default:
                    quad_acc<0>(ar[j], ai[j], xv0, t.x, t.y);
                    quad_acc<3>(ar[j], ai[j], xv1, t.x, t.y);
                    quad_acc<2>(ar[j], ai[j], xv2, t.x, t.y);
                    quad_acc<1>(ar[j], ai[j], xv3, t.x, t.y);
                    break;
            }
        }
    }
    int row = row0 + lane;
#pragma unroll
    for (int j = 0; j < NKY; ++j)
        A1[(KY0 + j)*65536 + row] = make_float2(ar[j], ai[j]);
}

__global__ __launch_bounds__(256) void fwd_w_kernel(const float* __restrict__ x,
                                                    float2* __restrict__ A1)
{
    __shared__ float2 tbl[256];
    __shared__ float xs[256*65];        // [w][row] padded
    int tid = threadIdx.x;
    tbl[tid] = make_float2(cospif(tid * (1.f/128.f)), -sinpif(tid * (1.f/128.f)));
    int row0 = blockIdx.x * 64;
    const float2* xf2 = (const float2*)x;
    for (int i2 = tid; i2 < 8192; i2 += 256) {
        int r = i2 >> 7, w2 = i2 & 127;
        float2 v = xf2[(size_t)(row0 + r)*128 + w2];
        xs[(2*w2)*65 + r]   = v.x;
        xs[(2*w2+1)*65 + r] = v.y;
    }
    __syncthreads();
    int lane = tid & 63, g = tid >> 6;
    if      (g == 0) fwdw_body<0, 5>(lane, row0, xs, tbl, A1);
    else if (g == 1) fwdw_body<5, 4>(lane, row0, xs, tbl, A1);
    else if (g == 2) fwdw_body<9, 4>(lane, row0, xs, tbl, A1);
    else             fwdw_body<13,4>(lane, row0, xs, tbl, A1);
}

// ================= forward partial DFT along h =================
// X[(kx*17+ky)*256+bi] = (1/65536) sum_h A1[ky][bi][h] e^{-2pi i (kx+112)h/256}
// Block = (ky, 8-bi group) -> 544 blocks. lanes = (bl in 8 bi, q in 8 h-octants).
// h = q*32+hh; octant factor e^{-2pi i j q/8} (kx0+112 = 0 mod 8) post-loop;
// q-sum via shfl_xor. LDS layout [q][hh][bl] stride 264 -> exact 2-way (free).
__global__ __launch_bounds__(256) void fwd_h_kernel(const float2* __restrict__ A1,
                                                    float2* __restrict__ X)
{
    __shared__ float2 tbl[256];
    __shared__ float as_re[8*264];
    __shared__ float as_im[8*264];
    int tid = threadIdx.x;
    int ky = blockIdx.x >> 5, bi0 = (blockIdx.x & 31) * 8;
    tbl[tid] = make_float2(cospif(tid * (1.f/128.f)), -sinpif(tid * (1.f/128.f)));
    for (int idx = tid; idx < 2048; idx += 256) {
        int b = idx >> 8, h = idx & 255;
        float2 v = A1[ky*65536 + (bi0 + b)*256 + h];
        int ad = (h >> 5)*264 + (h & 31)*8 + b;
        as_re[ad] = v.x; as_im[ad] = v.y;
    }
    __syncthreads();
    int lane = tid & 63, g = tid >> 6;
    int bl = lane & 7, q = lane >> 3;
    int kx0 = g * 8;
    float2 acc[8];
#pragma unroll
    for (int j = 0; j < 8; ++j) acc[j] = make_float2(0.f, 0.f);
    int base = q*264 + bl;
    for (int hh = 0; hh < 32; ++hh) {
        float ar = as_re[base + hh*8];
        float ai = as_im[base + hh*8];
#pragma unroll
        for (int j = 0; j < 8; ++j) {
            int kk = kx0 + j + 112;
            float2 t = tbl[(kk * hh) & 255];      // wave-uniform -> broadcast
            acc[j].x = fmaf(ar, t.x, fmaf(-ai, t.y, acc[j].x));
            acc[j].y = fmaf(ar, t.y, fmaf( ai, t.x, acc[j].y));
        }
    }
#pragma unroll
    for (int j = 0; j < 8; ++j) {
        // octant factor e^{-2pi i (j*q)/8}
        float a = (float)(j * q) * 0.25f;
        float2 f = make_float2(cospif(a), -sinpif(a));
        float2 v = cmul(acc[j], f);
        v.x += __shfl_xor(v.x, 8);  v.y += __shfl_xor(v.y, 8);
        v.x += __shfl_xor(v.x, 16); v.y += __shfl_xor(v.y, 16);
        v.x += __shfl_xor(v.x, 32); v.y += __shfl_xor(v.y, 32);
        acc[j] = v;
    }
    if (q == 0) {
        const float inv = 1.f / 65536.f;
#pragma unroll
        for (int j = 0; j < 8; ++j)
            X[((kx0 + j)*17 + ky)*256 + bi0 + bl] =
                make_float2(acc[j].x * inv, acc[j].y * inv);
    }
}

// ================= per-mode channel mixing =================
__global__ __launch_bounds__(256) void mix_kernel(const float2* __restrict__ X,
                                                  const float2* __restrict__ W4,
                                                  float2* __restrict__ Mx)
{
    __shared__ float2 Xs[256];
    __shared__ float2 Ws[1024];
    int tid = threadIdx.x, mode = blockIdx.x;
    Xs[tid] = X[mode*256 + tid];
    for (int idx = tid; idx < 1024; idx += 256) Ws[idx] = W4[mode*1024 + idx];
    __syncthreads();
    int b = tid >> 5, o = tid & 31;
    float2 acc = make_float2(0.f, 0.f);
#pragma unroll
    for (int i = 0; i < 32; ++i)
        acc = cfma(Xs[b*32 + i], Ws[i*32 + o], acc);
    Mx[mode*256 + tid] = acc;
}

// ================= fused inverse, h-split =================
// Grid: bo (256) x hc (4); block computes 64 h-rows of T then 64x256 outputs.
template<int KY0, int NK>
__device__ __forceinline__ void invh_part(int h, const float2* ms, float2* Ts)
{
    float2 acc[NK];
#pragma unroll
    for (int j = 0; j < NK; ++j) acc[j] = make_float2(0.f, 0.f);
    for (int kx = 0; kx < 32; ++kx) {
        int n = ((kx + 112) * h) & 255;
        float a = n * (1.f/128.f);
        float cc = cospif(a), ss = sinpif(a);      // e^{+i theta}
#pragma unroll
        for (int j = 0; j < NK; ++j) {
            float2 mv = ms[kx*17 + KY0 + j];       // wave-uniform broadcast
            acc[j].x = fmaf(mv.x, cc, fmaf(-mv.y, ss, acc[j].x));
            acc[j].y = fmaf(mv.x, ss, fmaf( mv.y, cc, acc[j].y));
        }
    }
#pragma unroll
    for (int j = 0; j < NK; ++j) Ts[(h & 63)*17 + KY0 + j] = acc[j];
}

__global__ __launch_bounds__(256) void inv_kernel(const float2* __restrict__ Mx,
                                                  const int* __restrict__ q_bias,
                                                  const float* __restrict__ b_scale,
                                                  const float* __restrict__ b_min,
                                                  float* __restrict__ out)
{
    __shared__ float2 ms[544];
    __shared__ float2 Ts[64*17];
    int tid = threadIdx.x;
    int bo = blockIdx.x & 255, hc = blockIdx.x >> 8;
    for (int idx = tid; idx < 544; idx += 256) ms[idx] = Mx[idx*256 + bo];
    __syncthreads();
    {   // phase 1: T[h][ky] = sum_kx Mx[kx][ky] e^{+2pi i (kx+112)h/256}
        int h = hc*64 + (tid & 63);
        int kg = tid >> 6;
        if      (kg == 0) invh_part<0, 4>(h, ms, Ts);
        else if (kg == 1) invh_part<4, 4>(h, ms, Ts);
        else if (kg == 2) invh_part<8, 4>(h, ms, Ts);
        else              invh_part<12,5>(h, ms, Ts);
    }
    __syncthreads();
    {   // phase 2: out[h][w] = 2*Re(sum_ky T[h][ky] e^{+2pi i (ky+56)w/256}) + bias
        int w = tid;
        float Ec[17], Es[17];
#pragma unroll
        for (int ky = 0; ky < 17; ++ky) {
            int n = ((ky + 56) * w) & 255;
            float a = n * (1.f/128.f);
            Ec[ky] = cospif(a);
            Es[ky] = -sinpif(a);
        }
        float bias = q_bias[bo & 31] * (*b_scale) + (*b_min);
        float* orow = out + (size_t)bo * 65536 + (size_t)hc * 64 * 256;
        for (int h = 0; h < 64; ++h) {
            float acc = 0.f;
#pragma unroll
            for (int ky = 0; ky < 17; ++ky) {
                float2 v = Ts[h*17 + ky];          // wave-uniform broadcast
                acc = fmaf(v.x, Ec[ky], acc);
                acc = fmaf(v.y, Es[ky], acc);
            }
            orow[h*256 + w] = fmaf(2.f, acc, bias);
        }
    }
}

extern "C" void kernel_launch(void* const* d_in, const int* in_sizes, int n_in,
                              void* d_out, int out_size, void* d_ws, size_t ws_size,
                              hipStream_t stream) {
    const float* x          = (const float*)d_in[0];
    const float* core_scale = (const float*)d_in[1];
    const float* core_min   = (const float*)d_in[2];
    const float* f_scales   = (const float*)d_in[3];
    const float* f_mins     = (const float*)d_in[4];
    const float* b_scale    = (const float*)d_in[5];
    const float* b_min      = (const float*)d_in[6];
    const int* q_core = (const int*)d_in[7];
    const int* q_f0   = (const int*)d_in[8];
    const int* q_f1   = (const int*)d_in[9];
    const int* q_f2   = (const int*)d_in[10];
    const int* q_f3   = (const int*)d_in[11];
    const int* q_bias = (const int*)d_in[12];
    float* out = (float*)d_out;

    float2* ws = (float2*)d_ws;
    float2* A1 = ws;                 // 1,114,112  [17][256 bi][256 h]
    float2* W4 = ws + 1114112;       //   557,056  [544][32][32]
    float2* X  = W4 + 557056;        //   139,264  [544][256]
    float2* Mx = X + 139264;         //   139,264  [544][256]
    (void)ws_size; (void)n_in; (void)in_sizes; (void)out_size;

    weights_kernel<<<544, 256, 0, stream>>>(q_core, q_f0, q_f1, q_f2, q_f3,
                                            core_scale, core_min, f_scales, f_mins, W4);
    fwd_w_kernel<<<1024, 256, 0, stream>>>(x, A1);
    fwd_h_kernel<<<544, 256, 0, stream>>>(A1, X);
    mix_kernel<<<544, 256, 0, stream>>>(X, W4, Mx);
    inv_kernel<<<1024, 256, 0, stream>>>(Mx, q_bias, b_scale, b_min, out);
}

// Round 4
// 237.423 us; speedup vs baseline: 1.1433x; 1.0054x over previous
//
#include <hip/hip_runtime.h>

// QuantizedSpectralConv on MI355X (gfx950).
// x [8,32,256,256] f32; Tucker: core[16,16,16,9] F0[32,16] F1[32,16] F2[32,16]
// F3[17,9] complex, deq = q*scale+min. Active window: kx in [112,144),
// ky in [56,73) of the (256,129) rfft2. norm="forward" (1/65536 on fwd).
//
// Workspace (float2):
//   A1 [17 ky][256 bi][256 h]; X [544 mode][256 bi]; W4 [544][32][32];
//   Mx [544 mode][256 bo];     CL [17 d][16 k][256 ij]  (F3-contracted core)
// LDS rule: addresses wave-uniform (broadcast) or lane-consecutive only.

__device__ __forceinline__ float2 cfma(float2 a, float2 b, float2 c) {
    c.x = fmaf(a.x, b.x, fmaf(-a.y, b.y, c.x));
    c.y = fmaf(a.x, b.y, fmaf(a.y, b.x, c.y));
    return c;
}
__device__ __forceinline__ float2 cmul(float2 a, float2 b) {
    return make_float2(a.x*b.x - a.y*b.y, a.x*b.y + a.y*b.x);
}

// ============ wprep: CL[d][k][ij] = sum_l core[ij,k,l] * F3[d,l] ============
__global__ __launch_bounds__(256) void wprep_kernel(
    const int* __restrict__ q_core, const int* __restrict__ q_f3,
    const float* __restrict__ core_scale, const float* __restrict__ core_min,
    const float* __restrict__ f_scales, const float* __restrict__ f_mins,
    float2* __restrict__ CL)
{
    int d = blockIdx.x >> 4, k = blockIdx.x & 15;   // grid 272
    int ij = threadIdx.x;
    float cs = *core_scale, cm = *core_min;
    float s3 = f_scales[3], m3 = f_mins[3];
    const int* qc = q_core + ((ij*16 + k)*9)*2;
    float2 acc = make_float2(0.f, 0.f);
#pragma unroll
    for (int l = 0; l < 9; ++l) {
        int2 q = *(const int2*)(qc + l*2);
        float2 ce = make_float2(q.x*cs + cm, q.y*cs + cm);
        float2 f3 = make_float2(q_f3[(d*9+l)*2]*s3 + m3, q_f3[(d*9+l)*2+1]*s3 + m3);
        acc = cfma(ce, f3, acc);
    }
    CL[(d*16 + k)*256 + ij] = acc;
}

// ============ weights: per-mode k/j/i contractions, CL coalesced ============
__global__ __launch_bounds__(256) void weights_kernel(
    const float2* __restrict__ CL, const int* __restrict__ q_f0,
    const int* __restrict__ q_f1, const int* __restrict__ q_f2,
    const float* __restrict__ f_scales, const float* __restrict__ f_mins,
    float2* __restrict__ W4)
{
    __shared__ float2 F0s[512], F1s[512];
    __shared__ float2 C2p[16*17];
    __shared__ float2 A2p[16*33];
    int t = threadIdx.x, m = blockIdx.x;
    int c = m / 17, d = m % 17;
    float s0 = f_scales[0], m0 = f_mins[0];
    float s1 = f_scales[1], m1 = f_mins[1];
    float s2 = f_scales[2], m2 = f_mins[2];

    for (int e = t; e < 512; e += 256) {
        F0s[e] = make_float2(q_f0[2*e]*s0 + m0, q_f0[2*e+1]*s0 + m0);
        F1s[e] = make_float2(q_f1[2*e]*s1 + m1, q_f1[2*e+1]*s1 + m1);
    }
    {   // phase 1: C2[i,j] = sum_k CL[d][k][ij] * F2[c,k]   (coalesced reads)
        float2 acc = make_float2(0.f, 0.f);
#pragma unroll
        for (int k = 0; k < 16; ++k) {
            float2 clv = CL[(d*16 + k)*256 + t];
            float2 f2 = make_float2(q_f2[(c*16+k)*2]*s2 + m2,
                                    q_f2[(c*16+k)*2+1]*s2 + m2);
            acc = cfma(clv, f2, acc);
        }
        __syncthreads();            // F0s/F1s ready; also before C2p write is fine
        C2p[(t >> 4)*17 + (t & 15)] = acc;
    }
    __syncthreads();
#pragma unroll
    for (int r = 0; r < 2; ++r) {   // phase 2: A2[i,b] = sum_j C2[i,j]*F1[b,j]
        int e = t + r*256; int i = e & 15, b = e >> 4;
        float2 acc = make_float2(0.f, 0.f);
#pragma unroll
        for (int j = 0; j < 16; ++j)
            acc = cfma(C2p[i*17 + j], F1s[b*16 + j], acc);
        A2p[i*33 + b] = acc;
    }
    __syncthreads();
    {   // phase 3: W4[m,a,b] = sum_i F0[a,i]*A2[i,b]
        int b = t & 31, a0 = t >> 5;
#pragma unroll
        for (int q = 0; q < 4; ++q) {
            int a = a0 + 8*q;
            float2 acc = make_float2(0.f, 0.f);
#pragma unroll
            for (int i = 0; i < 16; ++i)
                acc = cfma(F0s[a*16 + i], A2p[i*33 + b], acc);
            W4[m*1024 + a*32 + b] = acc;
        }
    }
}

// ================= forward partial DFT along w =================
// Register twiddle recurrence (no LDS table); quadrant signs wired.
template<int P>
__device__ __forceinline__ void quad_acc(float& ar, float& ai, float xv, float tx, float ty) {
    if (P == 0) { ar = fmaf(xv, tx, ar);  ai = fmaf(xv, ty, ai); }
    if (P == 1) { ar = fmaf(xv, ty, ar);  ai = fmaf(-xv, tx, ai); }   // *(-i)
    if (P == 2) { ar = fmaf(-xv, tx, ar); ai = fmaf(-xv, ty, ai); }   // *(-1)
    if (P == 3) { ar = fmaf(-xv, ty, ar); ai = fmaf(xv, tx, ai); }    // *(+i)
}

template<int KY0, int NKY>
__device__ __forceinline__ void fwdw_body(int lane, int row0, const float* xs,
                                          float2* __restrict__ A1)
{
    float ar[NKY], ai[NKY], tr[NKY], ti[NKY], sr[NKY], si[NKY];
#pragma unroll
    for (int j = 0; j < NKY; ++j) {
        ar[j] = 0.f; ai[j] = 0.f;
        const int kk = KY0 + j + 56;
        float a = kk * (1.f/128.f);
        sr[j] = cospif(a); si[j] = -sinpif(a);    // step e^{-2pi i kk/256}
        tr[j] = 1.f; ti[j] = 0.f;
    }
    for (int w = 0; w < 64; ++w) {
        float xv0 = xs[w*65 + lane];
        float xv1 = xs[(w+64)*65 + lane];
        float xv2 = xs[(w+128)*65 + lane];
        float xv3 = xs[(w+192)*65 + lane];
#pragma unroll
        for (int j = 0; j < NKY; ++j) {
            float tx = tr[j], ty = ti[j];
            const int pj = (KY0 + 56 + j) & 3;
            switch (pj) {
                case 0:
                    quad_acc<0>(ar[j], ai[j], xv0, tx, ty);
                    quad_acc<0>(ar[j], ai[j], xv1, tx, ty);
                    quad_acc<0>(ar[j], ai[j], xv2, tx, ty);
                    quad_acc<0>(ar[j], ai[j], xv3, tx, ty);
                    break;
                case 1:
                    quad_acc<0>(ar[j], ai[j], xv0, tx, ty);
                    quad_acc<1>(ar[j], ai[j], xv1, tx, ty);
                    quad_acc<2>(ar[j], ai[j], xv2, tx, ty);
                    quad_acc<3>(ar[j], ai[j], xv3, tx, ty);
                    break;
                case 2:
                    quad_acc<0>(ar[j], ai[j], xv0, tx, ty);
                    quad_acc<2>(ar[j], ai[j], xv1, tx, ty);
                    quad_acc<0>(ar[j], ai[j], xv2, tx, ty);
                    quad_acc<2>(ar[j], ai[j], xv3, tx, ty);
                    break;
                default:
                    quad_acc<0>(ar[j], ai[j], xv0, tx, ty);
                    quad_acc<3>(ar[j], ai[j], xv1, tx, ty);
                    quad_acc<2>(ar[j], ai[j], xv2, tx, ty);
                    quad_acc<1>(ar[j], ai[j], xv3, tx, ty);
                    break;
            }
            // advance twiddle: t *= step
            tr[j] = fmaf(tx, sr[j], -ty*si[j]);
            ti[j] = fmaf(tx, si[j],  ty*sr[j]);
        }
    }
    int row = row0 + lane;
#pragma unroll
    for (int j = 0; j < NKY; ++j)
        A1[(KY0 + j)*65536 + row] = make_float2(ar[j], ai[j]);
}

__global__ __launch_bounds__(256) void fwd_w_kernel(const float* __restrict__ x,
                                                    float2* __restrict__ A1)
{
    __shared__ float xs[256*65];        // [w][row] padded, conflict-free
    int tid = threadIdx.x;
    int row0 = blockIdx.x * 64;
    const float2* xf2 = (const float2*)x;
    for (int i2 = tid; i2 < 8192; i2 += 256) {
        int r = i2 >> 7, w2 = i2 & 127;
        float2 v = xf2[(size_t)(row0 + r)*128 + w2];
        xs[(2*w2)*65 + r]   = v.x;
        xs[(2*w2+1)*65 + r] = v.y;
    }
    __syncthreads();
    int lane = tid & 63, g = tid >> 6;
    if      (g == 0) fwdw_body<0, 5>(lane, row0, xs, A1);
    else if (g == 1) fwdw_body<5, 4>(lane, row0, xs, A1);
    else if (g == 2) fwdw_body<9, 4>(lane, row0, xs, A1);
    else             fwdw_body<13,4>(lane, row0, xs, A1);
}

// ================= forward partial DFT along h =================
__global__ __launch_bounds__(256) void fwd_h_kernel(const float2* __restrict__ A1,
                                                    float2* __restrict__ X)
{
    __shared__ float2 tbl[256];
    __shared__ float as_re[8*264];
    __shared__ float as_im[8*264];
    int tid = threadIdx.x;
    int ky = blockIdx.x >> 5, bi0 = (blockIdx.x & 31) * 8;
    tbl[tid] = make_float2(cospif(tid * (1.f/128.f)), -sinpif(tid * (1.f/128.f)));
    for (int idx = tid; idx < 2048; idx += 256) {
        int b = idx >> 8, h = idx & 255;
        float2 v = A1[ky*65536 + (bi0 + b)*256 + h];
        int ad = (h >> 5)*264 + (h & 31)*8 + b;
        as_re[ad] = v.x; as_im[ad] = v.y;
    }
    __syncthreads();
    int lane = tid & 63, g = tid >> 6;
    int bl = lane & 7, q = lane >> 3;
    int kx0 = g * 8;
    float2 acc[8];
#pragma unroll
    for (int j = 0; j < 8; ++j) acc[j] = make_float2(0.f, 0.f);
    int base = q*264 + bl;
    for (int hh = 0; hh < 32; ++hh) {
        float ar = as_re[base + hh*8];
        float ai = as_im[base + hh*8];
#pragma unroll
        for (int j = 0; j < 8; ++j) {
            int kk = kx0 + j + 112;
            float2 t = tbl[(kk * hh) & 255];      // wave-uniform broadcast
            acc[j].x = fmaf(ar, t.x, fmaf(-ai, t.y, acc[j].x));
            acc[j].y = fmaf(ar, t.y, fmaf( ai, t.x, acc[j].y));
        }
    }
#pragma unroll
    for (int j = 0; j < 8; ++j) {
        float a = (float)(j * q) * 0.25f;         // e^{-2pi i jq/8}
        float2 f = make_float2(cospif(a), -sinpif(a));
        float2 v = cmul(acc[j], f);
        v.x += __shfl_xor(v.x, 8);  v.y += __shfl_xor(v.y, 8);
        v.x += __shfl_xor(v.x, 16); v.y += __shfl_xor(v.y, 16);
        v.x += __shfl_xor(v.x, 32); v.y += __shfl_xor(v.y, 32);
        acc[j] = v;
    }
    if (q == 0) {
        const float inv = 1.f / 65536.f;
#pragma unroll
        for (int j = 0; j < 8; ++j)
            X[((kx0 + j)*17 + ky)*256 + bi0 + bl] =
                make_float2(acc[j].x * inv, acc[j].y * inv);
    }
}

// ================= per-mode channel mixing =================
__global__ __launch_bounds__(256) void mix_kernel(const float2* __restrict__ X,
                                                  const float2* __restrict__ W4,
                                                  float2* __restrict__ Mx)
{
    __shared__ float2 Xs[256];
    __shared__ float2 Ws[1024];
    int tid = threadIdx.x, mode = blockIdx.x;
    Xs[tid] = X[mode*256 + tid];
    for (int idx = tid; idx < 1024; idx += 256) Ws[idx] = W4[mode*1024 + idx];
    __syncthreads();
    int b = tid >> 5, o = tid & 31;
    float2 acc = make_float2(0.f, 0.f);
#pragma unroll
    for (int i = 0; i < 32; ++i)
        acc = cfma(Xs[b*32 + i], Ws[i*32 + o], acc);
    Mx[mode*256 + tid] = acc;
}

// ================= fused inverse, w-quadrant registers =================
// Grid 2048 = bo(256) x hc(8); block covers 32 h x 256 w.
template<int KY0, int NK>
__device__ __forceinline__ void invh_part(int h, int hh, const float2* ms, float2* Ts)
{
    float2 acc[NK];
#pragma unroll
    for (int j = 0; j < NK; ++j) acc[j] = make_float2(0.f, 0.f);
    for (int kx = 0; kx < 32; ++kx) {
        int n = ((kx + 112) * h) & 255;
        float a = n * (1.f/128.f);
        float cc = cospif(a), ss = sinpif(a);      // e^{+i theta}
#pragma unroll
        for (int j = 0; j < NK; ++j) {
            float2 mv = ms[kx*17 + KY0 + j];       // 2-way broadcast
            acc[j].x = fmaf(mv.x, cc, fmaf(-mv.y, ss, acc[j].x));
            acc[j].y = fmaf(mv.x, ss, fmaf( mv.y, cc, acc[j].y));
        }
    }
#pragma unroll
    for (int j = 0; j < NK; ++j) Ts[hh*18 + KY0 + j] = acc[j];
}

__global__ __launch_bounds__(256) void inv_kernel(const float2* __restrict__ Mx,
                                                  const int* __restrict__ q_bias,
                                                  const float* __restrict__ b_scale,
                                                  const float* __restrict__ b_min,
                                                  float* __restrict__ out)
{
    __shared__ float2 ms[544];
    __shared__ __align__(16) float2 Ts[32*18];     // rows padded to 18
    int tid = threadIdx.x;
    int bo = blockIdx.x & 255, hc = blockIdx.x >> 8;
    for (int idx = tid; idx < 544; idx += 256) ms[idx] = Mx[idx*256 + bo];
    __syncthreads();
    {   // phase 1: Ts[hh][ky] = sum_kx ms[kx][ky] e^{+2pi i (kx+112)h/256}
        int hh = tid & 31, g = tid >> 5;           // g in [0,8)
        int h = hc*32 + hh;
        if (g < 7) {
            switch (g) {
                case 0: invh_part<0, 2>(h, hh, ms, Ts); break;
                case 1: invh_part<2, 2>(h, hh, ms, Ts); break;
                case 2: invh_part<4, 2>(h, hh, ms, Ts); break;
                case 3: invh_part<6, 2>(h, hh, ms, Ts); break;
                case 4: invh_part<8, 2>(h, hh, ms, Ts); break;
                case 5: invh_part<10,2>(h, hh, ms, Ts); break;
                default:invh_part<12,2>(h, hh, ms, Ts); break;
            }
        } else {
            invh_part<14,3>(h, hh, ms, Ts);
        }
    }
    __syncthreads();
    {   // phase 2: out[h][w0+64q] = 2*Re(T[h]*e^{i th0}*i^{ky*q}) + bias
        int w0 = tid & 63, hs = tid >> 6;          // 4 h-subgroups of 8
        float C[17], S[17];
#pragma unroll
        for (int ky = 0; ky < 17; ++ky) {
            int n = ((ky + 56) * w0) & 255;
            float a = n * (1.f/128.f);
            C[ky] = cospif(a);
            S[ky] = sinpif(a);
        }
        float bias = q_bias[bo & 31] * (*b_scale) + (*b_min);
        float acc[8][4];
#pragma unroll
        for (int r = 0; r < 8; ++r)
#pragma unroll
            for (int q = 0; q < 4; ++q) acc[r][q] = 0.f;

#pragma unroll
        for (int r = 0; r < 8; ++r) {
            int hh = hs*8 + r;
            const float4* tp = (const float4*)&Ts[hh*18];
#pragma unroll
            for (int kp = 0; kp < 9; ++kp) {
                float vx0, vy0, vx1 = 0.f, vy1 = 0.f;
                if (kp < 8) {
                    float4 v4 = tp[kp];
                    vx0 = v4.x; vy0 = v4.y; vx1 = v4.z; vy1 = v4.w;
                } else {
                    float2 v2 = Ts[hh*18 + 16];
                    vx0 = v2.x; vy0 = v2.y;
                }
#pragma unroll
                for (int half = 0; half < 2; ++half) {
                    if (kp == 8 && half == 1) break;
                    const int ky = 2*kp + half;
                    float vx = half ? vx1 : vx0;
                    float vy = half ? vy1 : vy0;
                    float ur = fmaf(vx, C[ky], -vy*S[ky]);
                    float ui = fmaf(vx, S[ky],  vy*C[ky]);
#pragma unroll
                    for (int q = 0; q < 4; ++q) {
                        const int p = (ky*q) & 3;
                        acc[r][q] += (p == 0) ? ur : (p == 1) ? -ui
                                   : (p == 2) ? -ur : ui;
                    }
                }
            }
        }
        float* obase = out + (size_t)bo*65536 + (size_t)hc*32*256;
#pragma unroll
        for (int r = 0; r < 8; ++r) {
            int hh = hs*8 + r;
#pragma unroll
            for (int q = 0; q < 4; ++q)
                obase[hh*256 + w0 + 64*q] = fmaf(2.f, acc[r][q], bias);
        }
    }
}

extern "C" void kernel_launch(void* const* d_in, const int* in_sizes, int n_in,
                              void* d_out, int out_size, void* d_ws, size_t ws_size,
                              hipStream_t stream) {
    const float* x          = (const float*)d_in[0];
    const float* core_scale = (const float*)d_in[1];
    const float* core_min   = (const float*)d_in[2];
    const float* f_scales   = (const float*)d_in[3];
    const float* f_mins     = (const float*)d_in[4];
    const float* b_scale    = (const float*)d_in[5];
    const float* b_min      = (const float*)d_in[6];
    const int* q_core = (const int*)d_in[7];
    const int* q_f0   = (const int*)d_in[8];
    const int* q_f1   = (const int*)d_in[9];
    const int* q_f2   = (const int*)d_in[10];
    const int* q_f3   = (const int*)d_in[11];
    const int* q_bias = (const int*)d_in[12];
    float* out = (float*)d_out;

    float2* ws = (float2*)d_ws;
    float2* A1 = ws;                 // 1,114,112  [17][256 bi][256 h]
    float2* W4 = ws + 1114112;       //   557,056  [544][32][32]
    float2* X  = W4 + 557056;        //   139,264  [544][256]
    float2* Mx = X + 139264;         //   139,264  [544][256]
    float2* CL = Mx + 139264;        //    69,632  [17][16][256]
    (void)ws_size; (void)n_in; (void)in_sizes; (void)out_size;

    wprep_kernel<<<272, 256, 0, stream>>>(q_core, q_f3, core_scale, core_min,
                                          f_scales, f_mins, CL);
    weights_kernel<<<544, 256, 0, stream>>>(CL, q_f0, q_f1, q_f2,
                                            f_scales, f_mins, W4);
    fwd_w_kernel<<<1024, 256, 0, stream>>>(x, A1);
    fwd_h_kernel<<<544, 256, 0, stream>>>(A1, X);
    mix_kernel<<<544, 256, 0, stream>>>(X, W4, Mx);
    inv_kernel<<<2048, 256, 0, stream>>>(Mx, q_bias, b_scale, b_min, out);
}